// Round 8
// baseline (397.490 us; speedup 1.0000x reference)
//
#include <hip/hip_runtime.h>
#include <stdint.h>

#define N_TOK 4096
#define C_DIM 256

typedef __attribute__((ext_vector_type(8))) short short8;
typedef __attribute__((ext_vector_type(8))) _Float16 half8;
typedef __attribute__((ext_vector_type(4))) float floatx4;
typedef __attribute__((ext_vector_type(16))) float floatx16;
typedef __attribute__((ext_vector_type(4))) unsigned short ushort4v;

__device__ __forceinline__ unsigned short bf16_rne(float f) {
    union { float f; unsigned int u; } v; v.f = f;
    unsigned int u = v.u;
    unsigned int rounded = u + 0x7FFFu + ((u >> 16) & 1u);
    return (unsigned short)(rounded >> 16);
}
__device__ __forceinline__ float bf16_to_f(unsigned short h) {
    union { unsigned int u; float f; } v; v.u = ((unsigned int)h) << 16;
    return v.f;
}
__device__ __forceinline__ void split_bf16(float f, unsigned short& h, unsigned short& l) {
    h = bf16_rne(f);
    l = bf16_rne(f - bf16_to_f(h));
}
__device__ __forceinline__ unsigned short f2h(float f) {
    union { _Float16 h; unsigned short u; } v; v.h = (_Float16)f; return v.u;
}
__device__ __forceinline__ float h2f(unsigned short u) {
    union { unsigned short u; _Float16 h; } v; v.u = u; return (float)v.h;
}
// pack two floats -> half2 (RNE)
__device__ __forceinline__ unsigned int pack2h(float a, float b) {
    union { _Float16 h[2]; unsigned int u; } v;
    v.h[0] = (_Float16)a; v.h[1] = (_Float16)b;
    return v.u;
}
// async global->LDS 16B/lane; LDS dest = wave-uniform base + lane*16
__device__ __forceinline__ void g2l16(const void* g, void* l) {
    __builtin_amdgcn_global_load_lds(
        (const __attribute__((address_space(1))) void*)g,
        (__attribute__((address_space(3))) void*)l, 16, 0, 0);
}

// ---------------------------------------------------------------------------
// prep_kernel: one-time split/transpose (bf16 hi/lo pairs for fp32-accurate
// projection GEMM).  (unchanged)
// ---------------------------------------------------------------------------
__global__ __launch_bounds__(256) void prep_kernel(
    const float* __restrict__ x,
    const float* __restrict__ Wq, const float* __restrict__ Wk, const float* __restrict__ Wv,
    unsigned short* __restrict__ Xhi, unsigned short* __restrict__ Xlo,
    unsigned short* __restrict__ Whi, unsigned short* __restrict__ Wlo)
{
    const int t = threadIdx.x;
    if (blockIdx.x >= 1024) {
        const int pj = blockIdx.x - 1024;
        const float* W = (pj == 0) ? Wq : (pj == 1) ? Wk : Wv;
        unsigned short* dh = Whi + pj * 65536;
        unsigned short* dl = Wlo + pj * 65536;
        for (int it = 0; it < 64; it++) {
            const int idx = it * 1024 + t * 4;
            const float4 w = *(const float4*)&W[idx];
            unsigned short h0, l0, h1, l1, h2, l2, h3, l3;
            split_bf16(w.x, h0, l0); split_bf16(w.y, h1, l1);
            split_bf16(w.z, h2, l2); split_bf16(w.w, h3, l3);
            ushort4v vh; vh[0] = h0; vh[1] = h1; vh[2] = h2; vh[3] = h3;
            ushort4v vl; vl[0] = l0; vl[1] = l1; vl[2] = l2; vl[3] = l3;
            *(ushort4v*)&dh[idx] = vh;
            *(ushort4v*)&dl[idx] = vl;
        }
        return;
    }
    __shared__ float Xs[64 * 65];   // pitch 65: conflict-free transpose
    const int b  = blockIdx.x >> 8;
    const int ct = (blockIdx.x >> 6) & 3;
    const int nt = blockIdx.x & 63;
    const int c0 = ct * 64, n0 = nt * 64;
    {
        const int nch = t & 15, cr = t >> 4;
#pragma unroll
        for (int pass = 0; pass < 4; pass++) {
            const int c = pass * 16 + cr;
            const float4 v = *(const float4*)&x[((size_t)(b * C_DIM + c0 + c)) * N_TOK + n0 + nch * 4];
            float* row = &Xs[c * 65 + nch * 4];
            row[0] = v.x; row[1] = v.y; row[2] = v.z; row[3] = v.w;
        }
    }
    __syncthreads();
    {
        const int n = t >> 2, cc = t & 3;
        short8 vh0, vl0, vh1, vl1;
#pragma unroll
        for (int i = 0; i < 8; i++) {
            unsigned short h, l;
            split_bf16(Xs[(cc * 16 + i) * 65 + n], h, l);
            vh0[i] = (short)h; vl0[i] = (short)l;
        }
#pragma unroll
        for (int i = 0; i < 8; i++) {
            unsigned short h, l;
            split_bf16(Xs[(cc * 16 + 8 + i) * 65 + n], h, l);
            vh1[i] = (short)h; vl1[i] = (short)l;
        }
        const size_t off = ((size_t)b * N_TOK + n0 + n) * C_DIM + c0 + cc * 16;
        *(short8*)&Xhi[off] = vh0; *(short8*)&Xhi[off + 8] = vh1;
        *(short8*)&Xlo[off] = vl0; *(short8*)&Xlo[off + 8] = vl1;
    }
}

// ---------------------------------------------------------------------------
// proj_kernel: Out[n,o] = sum_c x[n,c]*W[o,c] + bias (+pos for K').
// ALL THREE outputs swizzled for direct coalesced fragment loads in flash:
//   Qh[b][qt=n>>7][phase=o>>3 (32)][q=n&127][i=o&7]
//   Kh[b][jt=n>>6][phase=o>>3 (32)][j=n&63][i=o&7]
//   Vh[b][jt=n>>6][phase=(n&63)>>3 (8)][c=o (256)][i=n&7]
// ---------------------------------------------------------------------------
__global__ __launch_bounds__(256) void proj_kernel(
    const unsigned short* __restrict__ Xhi, const unsigned short* __restrict__ Xlo,
    const unsigned short* __restrict__ Whi, const unsigned short* __restrict__ Wlo,
    const float* __restrict__ bq, const float* __restrict__ bk, const float* __restrict__ bv,
    const float* __restrict__ relh, const float* __restrict__ relw,
    unsigned short* __restrict__ Qh,
    unsigned short* __restrict__ Kh,
    unsigned short* __restrict__ Vh)
{
    __shared__ unsigned short SM[20480];   // 40KB carve
    unsigned short* Ah = SM;               // [64][32]
    unsigned short* Al = SM + 2048;
    unsigned short* Bh = SM + 4096;        // [256][32]
    unsigned short* Bl = SM + 12288;

    const int t    = threadIdx.x;
    const int wave = t >> 6;
    const int lane = t & 63;
    const int l15  = lane & 15;
    const int quad = lane >> 4;

    const int bp   = blockIdx.x >> 6;
    const int proj = bp % 3;
    const int b    = bp / 3;
    const int n0   = (blockIdx.x & 63) * 64;

    const unsigned short* Xh = Xhi + ((size_t)b * N_TOK + n0) * C_DIM;
    const unsigned short* Xl = Xlo + ((size_t)b * N_TOK + n0) * C_DIM;
    const unsigned short* Wh = Whi + proj * 65536;
    const unsigned short* Wl = Wlo + proj * 65536;
    const float* bias = (proj == 0) ? bq : (proj == 1) ? bk : bv;
    const bool needlo = (proj < 2);

    floatx4 acc[16];
#pragma unroll
    for (int i = 0; i < 16; i++) acc[i] = (floatx4){0.f, 0.f, 0.f, 0.f};

    for (int c0 = 0; c0 < 256; c0 += 32) {
        {
            const int lr = lane >> 2, cp = lane & 3;
            const int key = (lr ^ (lr >> 2)) & 3;
            const int r = wave * 16 + lr;
            g2l16(Xh + (size_t)r * C_DIM + c0 + (cp ^ key) * 8, &Ah[wave * 512]);
            if (needlo) g2l16(Xl + (size_t)r * C_DIM + c0 + (cp ^ key) * 8, &Al[wave * 512]);
#pragma unroll
            for (int p = 0; p < 4; p++) {
                const int rb = (p * 4 + wave) * 16;
                const int rr = rb + lr;
                g2l16(Wh + (size_t)rr * 256 + c0 + (cp ^ key) * 8, &Bh[rb * 32]);
                if (needlo) g2l16(Wl + (size_t)rr * 256 + c0 + (cp ^ key) * 8, &Bl[rb * 32]);
            }
        }
        __syncthreads();

        const int akey = (l15 ^ (l15 >> 2)) & 3;
        const int arow = (wave * 16 + l15) * 32 + ((quad ^ akey) * 8);
        const short8 a_h = *(const short8*)&Ah[arow];
        short8 a_l;
        if (needlo) a_l = *(const short8*)&Al[arow];
#pragma unroll
        for (int ot = 0; ot < 16; ot++) {
            const int brow = (ot * 16 + l15) * 32 + ((quad ^ akey) * 8);
            const short8 b_h = *(const short8*)&Bh[brow];
            acc[ot] = __builtin_amdgcn_mfma_f32_16x16x32_bf16(a_h, b_h, acc[ot], 0, 0, 0);
            if (needlo) {
                const short8 b_l = *(const short8*)&Bl[brow];
                acc[ot] = __builtin_amdgcn_mfma_f32_16x16x32_bf16(a_l, b_h, acc[ot], 0, 0, 0);
                acc[ot] = __builtin_amdgcn_mfma_f32_16x16x32_bf16(a_h, b_l, acc[ot], 0, 0, 0);
            }
        }
        __syncthreads();
    }

    // ---- epilogue (all fp16 outputs, swizzled layouts) ----
    const int h0 = n0 >> 6;   // pos[c][n] = relh[c][n>>6] + relw[c][n&63]
    if (proj == 0) {
        // Q: [qt][phase=o>>3][q128][i=o&7]
        unsigned short* Og = Qh + (size_t)b * N_TOK * C_DIM;
#pragma unroll
        for (int ot = 0; ot < 16; ot++) {
            const int o = ot * 16 + l15;
            const float bs = bias[o];
            const int phase = o >> 3;
            const int ii    = o & 7;
#pragma unroll
            for (int r = 0; r < 4; r++) {
                const int n  = n0 + wave * 16 + quad * 4 + r;
                const int qt = n >> 7, q128 = n & 127;
                Og[(size_t)qt * 32768 + phase * 1024 + q128 * 8 + ii] = f2h(acc[ot][r] + bs);
            }
        }
    } else if (proj == 1) {
        // K': [jt=n>>6][phase=o>>3][j=n&63][i=o&7]
        unsigned short* Og = Kh + (size_t)b * N_TOK * C_DIM;
        const int jt = n0 >> 6;
#pragma unroll
        for (int ot = 0; ot < 16; ot++) {
            const int o = ot * 16 + l15;
            const float bs = bias[o];
            const float ph = relh[o * 64 + h0];
            const int phase = o >> 3;
            const int ii    = o & 7;
#pragma unroll
            for (int r = 0; r < 4; r++) {
                const int nl = wave * 16 + quad * 4 + r;   // j within tile
                Og[(size_t)jt * 16384 + phase * 512 + nl * 8 + ii] =
                    f2h(acc[ot][r] + bs + ph + relw[o * 64 + nl]);
            }
        }
    } else {
        // V: LDS transpose (as before), then swizzled store
        // [jt=n0>>6][phase=ch (j-chunk)][c=o][i 8]
        unsigned short* Vt = SM;
#pragma unroll
        for (int ot = 0; ot < 16; ot++) {
            const int o = ot * 16 + l15;
            const float bs = bias[o];
            const unsigned int u0 = (unsigned int)f2h(acc[ot][0] + bs) |
                                    ((unsigned int)f2h(acc[ot][1] + bs) << 16);
            const unsigned int u1 = (unsigned int)f2h(acc[ot][2] + bs) |
                                    ((unsigned int)f2h(acc[ot][3] + bs) << 16);
            uint2 uv; uv.x = u0; uv.y = u1;
            *(uint2*)&Vt[o * 72 + wave * 16 + quad * 4] = uv;
        }
        __syncthreads();
        const int ch   = t & 7;     // j-chunk (phase)
        const int orow = t >> 3;
        const int jt   = n0 >> 6;
        unsigned short* Og = Vh + (size_t)b * N_TOK * C_DIM + (size_t)jt * 16384;
#pragma unroll
        for (int pass = 0; pass < 8; pass++) {
            const int o = pass * 32 + orow;
            const short8 vv = *(const short8*)&Vt[o * 72 + ch * 8];
            *(short8*)&Og[ch * 2048 + o * 8] = vv;
        }
    }
}

// ---------------------------------------------------------------------------
// flash_kernel v9b: v9 with the Q-staging stride bug fixed.
// r7 FAILED (NaN) because the staging loop used chunk = (p*4+wave)*2048
// halves -- 4x the correct stride -- overrunning the 32768-half LDS buffer
// and leaving 3/4 of the Q tile unstaged.  Each g2l16 call writes 64 lanes
// x 16B = 512 halves, so the correct chunk stride is 512.
// Structure (from r6 register model, unchanged): c-split blocks -> oacc 64
// AGPR; launch_bounds(256,2) caps arch at 128; 64 free AGPRs absorb arch
// overflow; K,V direct from pre-swizzled global (L1/L2); Q staged once to
// 64KB LDS; zero per-iteration barriers.
// ---------------------------------------------------------------------------
template<int NS>
__global__ __launch_bounds__(256, 2) void flash_kernel(
    const unsigned short* __restrict__ Qg,   // swizzled [4][32][32][128][8]
    const unsigned short* __restrict__ Kg,   // swizzled [4][64][32][64][8]
    const unsigned short* __restrict__ Vg,   // swizzled [4][64][8][256][8]
    unsigned short* __restrict__ Op,         // fp16 [NS][4][256][4096]
    float* __restrict__ Lm)                  // [NS][4][4096] float2 (m,l)
{
    constexpr int NITER = N_TOK / (NS * 64);
    constexpr int SB    = (NS == 4) ? 2 : 1;

    __shared__ unsigned short Qs[32768];   // 64KB [phase32][q128][8]

    const int t    = threadIdx.x;
    const int wave = t >> 6;
    const int lane = t & 63;
    const int l31  = lane & 31;
    const int H    = lane >> 5;

    const int bid = blockIdx.x;
    const int b   = bid & 3;
    const int s   = (bid >> 2) & (NS - 1);
    const int r2  = bid >> (2 + SB);
    const int ch  = r2 & 1;          // c-half
    const int qt  = r2 >> 1;         // 0..31

    const size_t bbase = (size_t)b * N_TOK * C_DIM;
    const unsigned short* Kb = Kg + bbase;
    const unsigned short* Vb = Vg + bbase;

    // ---- stage Q tile once (64KB, coalesced 16B/lane)
    // each g2l16: 64 lanes x 8 halves = 512 halves -> chunk stride 512
    {
        const unsigned short* Qw = Qg + bbase + (size_t)qt * 32768;
#pragma unroll
        for (int p = 0; p < 16; p++) {
            const int chunk = (p * 4 + wave) * 512;
            g2l16(Qw + chunk + lane * 8, &Qs[chunk]);
        }
    }

    floatx16 oacc[4];   // O^T[c = ch*128 + cb*32 + row(r,H)][q=l31]
#pragma unroll
    for (int cb = 0; cb < 4; cb++)
#pragma unroll
        for (int r = 0; r < 16; r++) oacc[cb][r] = 0.f;
    float m_i = -1e30f;
    float l_i = 0.f;

    const int jt0  = s * NITER;
    const int qoff = (wave * 32 + l31) * 8;
    const int voff = (ch * 128 + l31) * 8;

    __syncthreads();   // Q tile visible (only barrier in the kernel)

    for (int ti = 0; ti < NITER; ti++) {
        const unsigned short* Kt = Kb + (size_t)(jt0 + ti) * 16384;
        const unsigned short* Vt = Vb + (size_t)(jt0 + ti) * 16384;

        // ---- S^T = K' Q^T : A-frags direct from swizzled global (L1/L2)
        floatx16 sv0, sv1;
        {
            floatx16 a0, a1;
#pragma unroll
            for (int r = 0; r < 16; r++) { a0[r] = 0.f; a1[r] = 0.f; }
            __builtin_amdgcn_s_setprio(1);
#pragma unroll
            for (int ct = 0; ct < 16; ct++) {
                const int ph = (ct * 2 + H);
                const half8 qv = *(const half8*)&Qs[ph * 1024 + qoff];
                const half8 k0 = *(const half8*)&Kt[ph * 512 + l31 * 8];
                a0 = __builtin_amdgcn_mfma_f32_32x32x16_f16(k0, qv, a0, 0, 0, 0);
                const half8 k1 = *(const half8*)&Kt[ph * 512 + 256 + l31 * 8];
                a1 = __builtin_amdgcn_mfma_f32_32x32x16_f16(k1, qv, a1, 0, 0, 0);
            }
            __builtin_amdgcn_s_setprio(0);
            sv0 = a0; sv1 = a1;
        }

        // ---- per-lane online softmax (32 j's/lane; partner lane^32)
        float mx = sv0[0];
#pragma unroll
        for (int r = 1; r < 16; r++) mx = fmaxf(mx, sv0[r]);
#pragma unroll
        for (int r = 0; r < 16; r++) mx = fmaxf(mx, sv1[r]);
        mx = fmaxf(mx, __shfl_xor(mx, 32));

        // T13 defer-max
        if (!__all(mx <= m_i + 8.f)) {
            const float mn    = fmaxf(m_i, mx);
            const float alpha = __expf(m_i - mn);
            m_i = mn;
            l_i *= alpha;
#pragma unroll
            for (int cb = 0; cb < 4; cb++)
#pragma unroll
                for (int r = 0; r < 16; r++) oacc[cb][r] *= alpha;
        }
        float ps = 0.f;
#pragma unroll
        for (int r = 0; r < 16; r++) {
            const float p = __expf(sv0[r] - m_i);
            sv0[r] = p; ps += p;
        }
#pragma unroll
        for (int r = 0; r < 16; r++) {
            const float p = __expf(sv1[r] - m_i);
            sv1[r] = p; ps += p;
        }
        l_i += ps;

        // ---- P^T -> PV B-frags (validated v6/v8 butterfly)
        half8 pf0, pf1, pf2, pf3;
        {
            const unsigned int p0 = pack2h(sv0[0],  sv0[1]);
            const unsigned int p1 = pack2h(sv0[2],  sv0[3]);
            const unsigned int p2 = pack2h(sv0[4],  sv0[5]);
            const unsigned int p3 = pack2h(sv0[6],  sv0[7]);
            const unsigned int p4 = pack2h(sv0[8],  sv0[9]);
            const unsigned int p5 = pack2h(sv0[10], sv0[11]);
            const unsigned int p6 = pack2h(sv0[12], sv0[13]);
            const unsigned int p7 = pack2h(sv0[14], sv0[15]);
            const unsigned int s0 = __shfl_xor(p0, 32);
            const unsigned int s1 = __shfl_xor(p1, 32);
            const unsigned int s2 = __shfl_xor(p2, 32);
            const unsigned int s3 = __shfl_xor(p3, 32);
            const unsigned int s4 = __shfl_xor(p4, 32);
            const unsigned int s5 = __shfl_xor(p5, 32);
            const unsigned int s6 = __shfl_xor(p6, 32);
            const unsigned int s7 = __shfl_xor(p7, 32);
            union { unsigned int u[4]; half8 h; } a, c;
            a.u[0] = H ? s2 : p0;  a.u[1] = H ? s3 : p1;
            a.u[2] = H ? p2 : s0;  a.u[3] = H ? p3 : s1;
            c.u[0] = H ? s6 : p4;  c.u[1] = H ? s7 : p5;
            c.u[2] = H ? p6 : s4;  c.u[3] = H ? p7 : s5;
            pf0 = a.h; pf1 = c.h;
        }
        {
            const unsigned int p0 = pack2h(sv1[0],  sv1[1]);
            const unsigned int p1 = pack2h(sv1[2],  sv1[3]);
            const unsigned int p2 = pack2h(sv1[4],  sv1[5]);
            const unsigned int p3 = pack2h(sv1[6],  sv1[7]);
            const unsigned int p4 = pack2h(sv1[8],  sv1[9]);
            const unsigned int p5 = pack2h(sv1[10], sv1[11]);
            const unsigned int p6 = pack2h(sv1[12], sv1[13]);
            const unsigned int p7 = pack2h(sv1[14], sv1[15]);
            const unsigned int s0 = __shfl_xor(p0, 32);
            const unsigned int s1 = __shfl_xor(p1, 32);
            const unsigned int s2 = __shfl_xor(p2, 32);
            const unsigned int s3 = __shfl_xor(p3, 32);
            const unsigned int s4 = __shfl_xor(p4, 32);
            const unsigned int s5 = __shfl_xor(p5, 32);
            const unsigned int s6 = __shfl_xor(p6, 32);
            const unsigned int s7 = __shfl_xor(p7, 32);
            union { unsigned int u[4]; half8 h; } a, c;
            a.u[0] = H ? s2 : p0;  a.u[1] = H ? s3 : p1;
            a.u[2] = H ? p2 : s0;  a.u[3] = H ? p3 : s1;
            c.u[0] = H ? s6 : p4;  c.u[1] = H ? s7 : p5;
            c.u[2] = H ? p6 : s4;  c.u[3] = H ? p7 : s5;
            pf2 = a.h; pf3 = c.h;
        }

        // ---- O^T += V P^T : A-frags direct from swizzled global (c-half)
        __builtin_amdgcn_s_setprio(1);
#pragma unroll
        for (int cb = 0; cb < 4; cb++) {
            const int cc = voff + cb * 256;
            const half8 av0 = *(const half8*)&Vt[(0 + H) * 2048 + cc];
            oacc[cb] = __builtin_amdgcn_mfma_f32_32x32x16_f16(av0, pf0, oacc[cb], 0, 0, 0);
            const half8 av1 = *(const half8*)&Vt[(2 + H) * 2048 + cc];
            oacc[cb] = __builtin_amdgcn_mfma_f32_32x32x16_f16(av1, pf1, oacc[cb], 0, 0, 0);
            const half8 av2 = *(const half8*)&Vt[(4 + H) * 2048 + cc];
            oacc[cb] = __builtin_amdgcn_mfma_f32_32x32x16_f16(av2, pf2, oacc[cb], 0, 0, 0);
            const half8 av3 = *(const half8*)&Vt[(6 + H) * 2048 + cc];
            oacc[cb] = __builtin_amdgcn_mfma_f32_32x32x16_f16(av3, pf3, oacc[cb], 0, 0, 0);
        }
        __builtin_amdgcn_s_setprio(0);
    }

    // ---- epilogue: unnormalized O^T fp16 + (m,l)
    unsigned short* Ob = Op + ((size_t)(s * 4 + b) * C_DIM) * N_TOK;
    const int n = qt * 128 + wave * 32 + l31;
#pragma unroll
    for (int cb = 0; cb < 4; cb++) {
#pragma unroll
        for (int r = 0; r < 16; r++) {
            const int c = ch * 128 + cb * 32 + (r & 3) + 8 * (r >> 2) + 4 * H;
            Ob[(size_t)c * N_TOK + n] = f2h(oacc[cb][r]);
        }
    }
    if (ch == 0) {
        float lt = l_i + __shfl_xor(l_i, 32);
        if (H == 0) {
            const size_t nb = (size_t)(s * 4 + b) * N_TOK + n;
            *(float2*)&Lm[nb * 2] = make_float2(m_i, lt);
        }
    }
}

// ---------------------------------------------------------------------------
// merge_kernel: out = gamma * (sum_s w_s O_s) / (sum_s w_s l_s) + x
// ---------------------------------------------------------------------------
template<int NS>
__global__ __launch_bounds__(256) void merge_kernel(
    const unsigned short* __restrict__ Op,
    const float* __restrict__ Lm,
    const float* __restrict__ x,
    const float* __restrict__ gamma,
    float* __restrict__ out)
{
    const int blk = blockIdx.x;          // 4096
    const int b   = blk >> 10;
    const int c   = (blk >> 2) & 255;
    const int nq  = blk & 3;
    const int n0  = nq * 1024 + threadIdx.x * 4;

    const size_t NEo = (size_t)4 * C_DIM * N_TOK;
    const size_t obase = ((size_t)b * C_DIM + c) * N_TOK + n0;

    float ms[NS][4], ls[NS][4], os[NS][4];
#pragma unroll
    for (int s = 0; s < NS; s++) {
        const uint2 u = *(const uint2*)&Op[s * NEo + obase];
        os[s][0] = h2f((unsigned short)(u.x & 0xffff));
        os[s][1] = h2f((unsigned short)(u.x >> 16));
        os[s][2] = h2f((unsigned short)(u.y & 0xffff));
        os[s][3] = h2f((unsigned short)(u.y >> 16));
        const float* Lms = Lm + (size_t)(s * 4 + b) * N_TOK * 2;
        const float4 A0 = *(const float4*)&Lms[n0 * 2];
        const float4 A1 = *(const float4*)&Lms[n0 * 2 + 4];
        ms[s][0] = A0.x; ls[s][0] = A0.y;
        ms[s][1] = A0.z; ls[s][1] = A0.w;
        ms[s][2] = A1.x; ls[s][2] = A1.y;
        ms[s][3] = A1.z; ls[s][3] = A1.w;
    }
    const float4 xv = *(const float4*)&x[obase];
    const float xin[4] = {xv.x, xv.y, xv.z, xv.w};
    const float g = gamma[0];

    float4 res;
    float* rp = (float*)&res;
#pragma unroll
    for (int i = 0; i < 4; i++) {
        float M = ms[0][i];
#pragma unroll
        for (int s = 1; s < NS; s++) M = fmaxf(M, ms[s][i]);
        float osum = 0.f, lsum = 0.f;
#pragma unroll
        for (int s = 0; s < NS; s++) {
            const float w = __expf(ms[s][i] - M);
            osum += w * os[s][i];
            lsum += w * ls[s][i];
        }
        rp[i] = g * osum / lsum + xin[i];
    }
    *(float4*)&out[obase] = res;
}

extern "C" void kernel_launch(void* const* d_in, const int* in_sizes, int n_in,
                              void* d_out, int out_size, void* d_ws, size_t ws_size,
                              hipStream_t stream) {
    const float* x     = (const float*)d_in[0];
    const float* Wq    = (const float*)d_in[1];
    const float* bq    = (const float*)d_in[2];
    const float* Wk    = (const float*)d_in[3];
    const float* bk    = (const float*)d_in[4];
    const float* Wv    = (const float*)d_in[5];
    const float* bv    = (const float*)d_in[6];
    const float* relh  = (const float*)d_in[7];
    const float* relw  = (const float*)d_in[8];
    const float* gamma = (const float*)d_in[9];
    float* out = (float*)d_out;

    const size_t NE = (size_t)4 * N_TOK * C_DIM;   // 4.19M elems

    // NS=4 needs: Op 4NE u16 + W 6*65536 u16 + QKV 3NE u16 + Lm 4*4*4096*2 f32
    const size_t need4 = ((size_t)7 * NE + 6 * 65536) * 2 + (size_t)4 * 4 * N_TOK * 2 * 4;
    const int NS = (ws_size >= need4) ? 4 : 2;

    // Region layout (Op overlays Xhi/Xlo: X dead before flash writes Op)
    unsigned short* Op  = (unsigned short*)d_ws;           // NS*NE u16
    unsigned short* Xhi = Op;                              // NE u16 (prep/proj only)
    unsigned short* Xlo = Op + NE;                         // NE u16
    unsigned short* Whi = Op + (size_t)NS * NE;            // 3*65536 u16
    unsigned short* Wlo = Whi + 3 * 65536;
    unsigned short* Qh  = Wlo + 3 * 65536;                 // NE u16 (fp16, swizzled)
    unsigned short* Kh  = Qh + NE;                         // NE u16 (fp16, swizzled)
    unsigned short* Vh  = Kh + NE;                         // NE u16 (fp16, swizzled)
    float* Lm = (float*)(Vh + NE);                         // NS*4*4096*2 floats

    hipLaunchKernelGGL(prep_kernel, dim3(1027), dim3(256), 0, stream,
                       x, Wq, Wk, Wv, Xhi, Xlo, Whi, Wlo);
    hipLaunchKernelGGL(proj_kernel, dim3(768), dim3(256), 0, stream,
                       Xhi, Xlo, Whi, Wlo, bq, bk, bv, relh, relw, Qh, Kh, Vh);
    if (NS == 4) {
        hipLaunchKernelGGL((flash_kernel<4>), dim3(1024), dim3(256), 0, stream,
                           Qh, Kh, Vh, Op, Lm);
        hipLaunchKernelGGL((merge_kernel<4>), dim3(4096), dim3(256), 0, stream,
                           Op, Lm, x, gamma, out);
    } else {
        hipLaunchKernelGGL((flash_kernel<2>), dim3(512), dim3(256), 0, stream,
                           Qh, Kh, Vh, Op, Lm);
        hipLaunchKernelGGL((merge_kernel<2>), dim3(4096), dim3(256), 0, stream,
                           Op, Lm, x, gamma, out);
    }
}

// Round 9
// 386.538 us; speedup vs baseline: 1.0283x; 1.0283x over previous
//
#include <hip/hip_runtime.h>
#include <stdint.h>

#define N_TOK 4096
#define C_DIM 256

typedef __attribute__((ext_vector_type(8))) short short8;
typedef __attribute__((ext_vector_type(8))) _Float16 half8;
typedef __attribute__((ext_vector_type(4))) float floatx4;
typedef __attribute__((ext_vector_type(16))) float floatx16;
typedef __attribute__((ext_vector_type(4))) unsigned short ushort4v;

__device__ __forceinline__ unsigned short bf16_rne(float f) {
    union { float f; unsigned int u; } v; v.f = f;
    unsigned int u = v.u;
    unsigned int rounded = u + 0x7FFFu + ((u >> 16) & 1u);
    return (unsigned short)(rounded >> 16);
}
__device__ __forceinline__ float bf16_to_f(unsigned short h) {
    union { unsigned int u; float f; } v; v.u = ((unsigned int)h) << 16;
    return v.f;
}
__device__ __forceinline__ void split_bf16(float f, unsigned short& h, unsigned short& l) {
    h = bf16_rne(f);
    l = bf16_rne(f - bf16_to_f(h));
}
__device__ __forceinline__ unsigned short f2h(float f) {
    union { _Float16 h; unsigned short u; } v; v.h = (_Float16)f; return v.u;
}
__device__ __forceinline__ float h2f(unsigned short u) {
    union { unsigned short u; _Float16 h; } v; v.u = u; return (float)v.h;
}
// pack two floats -> half2 (RNE)
__device__ __forceinline__ unsigned int pack2h(float a, float b) {
    union { _Float16 h[2]; unsigned int u; } v;
    v.h[0] = (_Float16)a; v.h[1] = (_Float16)b;
    return v.u;
}
// async global->LDS 16B/lane; LDS dest = wave-uniform base + lane*16
__device__ __forceinline__ void g2l16(const void* g, void* l) {
    __builtin_amdgcn_global_load_lds(
        (const __attribute__((address_space(1))) void*)g,
        (__attribute__((address_space(3))) void*)l, 16, 0, 0);
}

// ---------------------------------------------------------------------------
// prep_kernel: one-time split/transpose (bf16 hi/lo pairs for fp32-accurate
// projection GEMM).  (unchanged)
// ---------------------------------------------------------------------------
__global__ __launch_bounds__(256) void prep_kernel(
    const float* __restrict__ x,
    const float* __restrict__ Wq, const float* __restrict__ Wk, const float* __restrict__ Wv,
    unsigned short* __restrict__ Xhi, unsigned short* __restrict__ Xlo,
    unsigned short* __restrict__ Whi, unsigned short* __restrict__ Wlo)
{
    const int t = threadIdx.x;
    if (blockIdx.x >= 1024) {
        const int pj = blockIdx.x - 1024;
        const float* W = (pj == 0) ? Wq : (pj == 1) ? Wk : Wv;
        unsigned short* dh = Whi + pj * 65536;
        unsigned short* dl = Wlo + pj * 65536;
        for (int it = 0; it < 64; it++) {
            const int idx = it * 1024 + t * 4;
            const float4 w = *(const float4*)&W[idx];
            unsigned short h0, l0, h1, l1, h2, l2, h3, l3;
            split_bf16(w.x, h0, l0); split_bf16(w.y, h1, l1);
            split_bf16(w.z, h2, l2); split_bf16(w.w, h3, l3);
            ushort4v vh; vh[0] = h0; vh[1] = h1; vh[2] = h2; vh[3] = h3;
            ushort4v vl; vl[0] = l0; vl[1] = l1; vl[2] = l2; vl[3] = l3;
            *(ushort4v*)&dh[idx] = vh;
            *(ushort4v*)&dl[idx] = vl;
        }
        return;
    }
    __shared__ float Xs[64 * 65];   // pitch 65: conflict-free transpose
    const int b  = blockIdx.x >> 8;
    const int ct = (blockIdx.x >> 6) & 3;
    const int nt = blockIdx.x & 63;
    const int c0 = ct * 64, n0 = nt * 64;
    {
        const int nch = t & 15, cr = t >> 4;
#pragma unroll
        for (int pass = 0; pass < 4; pass++) {
            const int c = pass * 16 + cr;
            const float4 v = *(const float4*)&x[((size_t)(b * C_DIM + c0 + c)) * N_TOK + n0 + nch * 4];
            float* row = &Xs[c * 65 + nch * 4];
            row[0] = v.x; row[1] = v.y; row[2] = v.z; row[3] = v.w;
        }
    }
    __syncthreads();
    {
        const int n = t >> 2, cc = t & 3;
        short8 vh0, vl0, vh1, vl1;
#pragma unroll
        for (int i = 0; i < 8; i++) {
            unsigned short h, l;
            split_bf16(Xs[(cc * 16 + i) * 65 + n], h, l);
            vh0[i] = (short)h; vl0[i] = (short)l;
        }
#pragma unroll
        for (int i = 0; i < 8; i++) {
            unsigned short h, l;
            split_bf16(Xs[(cc * 16 + 8 + i) * 65 + n], h, l);
            vh1[i] = (short)h; vl1[i] = (short)l;
        }
        const size_t off = ((size_t)b * N_TOK + n0 + n) * C_DIM + c0 + cc * 16;
        *(short8*)&Xhi[off] = vh0; *(short8*)&Xhi[off + 8] = vh1;
        *(short8*)&Xlo[off] = vl0; *(short8*)&Xlo[off + 8] = vl1;
    }
}

// ---------------------------------------------------------------------------
// proj_kernel: Out[n,o] = sum_c x[n,c]*W[o,c] + bias (+pos for K').
// Q swizzled for register-fragment loads:  Qh[b][qt=n>>7][phase=o>>3][q=n&127][i=o&7]
// K,V back to the round-2 (v4) layouts for LDS staging:
//   Kh[b][n][o] (k+pos),  Vh[b][o][n]
// ---------------------------------------------------------------------------
__global__ __launch_bounds__(256) void proj_kernel(
    const unsigned short* __restrict__ Xhi, const unsigned short* __restrict__ Xlo,
    const unsigned short* __restrict__ Whi, const unsigned short* __restrict__ Wlo,
    const float* __restrict__ bq, const float* __restrict__ bk, const float* __restrict__ bv,
    const float* __restrict__ relh, const float* __restrict__ relw,
    unsigned short* __restrict__ Qh,
    unsigned short* __restrict__ Kh,
    unsigned short* __restrict__ Vh)
{
    __shared__ unsigned short SM[20480];   // 40KB carve
    unsigned short* Ah = SM;               // [64][32]
    unsigned short* Al = SM + 2048;
    unsigned short* Bh = SM + 4096;        // [256][32]
    unsigned short* Bl = SM + 12288;

    const int t    = threadIdx.x;
    const int wave = t >> 6;
    const int lane = t & 63;
    const int l15  = lane & 15;
    const int quad = lane >> 4;

    const int bp   = blockIdx.x >> 6;
    const int proj = bp % 3;
    const int b    = bp / 3;
    const int n0   = (blockIdx.x & 63) * 64;

    const unsigned short* Xh = Xhi + ((size_t)b * N_TOK + n0) * C_DIM;
    const unsigned short* Xl = Xlo + ((size_t)b * N_TOK + n0) * C_DIM;
    const unsigned short* Wh = Whi + proj * 65536;
    const unsigned short* Wl = Wlo + proj * 65536;
    const float* bias = (proj == 0) ? bq : (proj == 1) ? bk : bv;
    const bool needlo = (proj < 2);

    floatx4 acc[16];
#pragma unroll
    for (int i = 0; i < 16; i++) acc[i] = (floatx4){0.f, 0.f, 0.f, 0.f};

    for (int c0 = 0; c0 < 256; c0 += 32) {
        {
            const int lr = lane >> 2, cp = lane & 3;
            const int key = (lr ^ (lr >> 2)) & 3;
            const int r = wave * 16 + lr;
            g2l16(Xh + (size_t)r * C_DIM + c0 + (cp ^ key) * 8, &Ah[wave * 512]);
            if (needlo) g2l16(Xl + (size_t)r * C_DIM + c0 + (cp ^ key) * 8, &Al[wave * 512]);
#pragma unroll
            for (int p = 0; p < 4; p++) {
                const int rb = (p * 4 + wave) * 16;
                const int rr = rb + lr;
                g2l16(Wh + (size_t)rr * 256 + c0 + (cp ^ key) * 8, &Bh[rb * 32]);
                if (needlo) g2l16(Wl + (size_t)rr * 256 + c0 + (cp ^ key) * 8, &Bl[rb * 32]);
            }
        }
        __syncthreads();

        const int akey = (l15 ^ (l15 >> 2)) & 3;
        const int arow = (wave * 16 + l15) * 32 + ((quad ^ akey) * 8);
        const short8 a_h = *(const short8*)&Ah[arow];
        short8 a_l;
        if (needlo) a_l = *(const short8*)&Al[arow];
#pragma unroll
        for (int ot = 0; ot < 16; ot++) {
            const int brow = (ot * 16 + l15) * 32 + ((quad ^ akey) * 8);
            const short8 b_h = *(const short8*)&Bh[brow];
            acc[ot] = __builtin_amdgcn_mfma_f32_16x16x32_bf16(a_h, b_h, acc[ot], 0, 0, 0);
            if (needlo) {
                const short8 b_l = *(const short8*)&Bl[brow];
                acc[ot] = __builtin_amdgcn_mfma_f32_16x16x32_bf16(a_l, b_h, acc[ot], 0, 0, 0);
                acc[ot] = __builtin_amdgcn_mfma_f32_16x16x32_bf16(a_h, b_l, acc[ot], 0, 0, 0);
            }
        }
        __syncthreads();
    }

    // ---- epilogue (all fp16 outputs) ----
    const int h0 = n0 >> 6;   // pos[c][n] = relh[c][n>>6] + relw[c][n&63]
    if (proj == 0) {
        // swizzled Q: [qt][phase=o>>3][q128][i=o&7]
        unsigned short* Og = Qh + (size_t)b * N_TOK * C_DIM;
#pragma unroll
        for (int ot = 0; ot < 16; ot++) {
            const int o = ot * 16 + l15;
            const float bs = bias[o];
            const int phase = o >> 3;
            const int ii    = o & 7;
#pragma unroll
            for (int r = 0; r < 4; r++) {
                const int n  = n0 + wave * 16 + quad * 4 + r;
                const int qt = n >> 7, q128 = n & 127;
                Og[(size_t)qt * 32768 + phase * 1024 + q128 * 8 + ii] = f2h(acc[ot][r] + bs);
            }
        }
    } else if (proj == 1) {
        // K' row-major [n][o] (round-2 layout)
        unsigned short* Og = Kh + ((size_t)b * N_TOK + n0) * C_DIM;
#pragma unroll
        for (int ot = 0; ot < 16; ot++) {
            const int o = ot * 16 + l15;
            const float bs = bias[o];
            const float ph = relh[o * 64 + h0];
#pragma unroll
            for (int r = 0; r < 4; r++) {
                const int nl = wave * 16 + quad * 4 + r;
                Og[(size_t)nl * C_DIM + o] = f2h(acc[ot][r] + bs + ph + relw[o * 64 + nl]);
            }
        }
    } else {
        // V [o][n] via LDS transpose (round-2 layout)
        unsigned short* Vt = SM;
#pragma unroll
        for (int ot = 0; ot < 16; ot++) {
            const int o = ot * 16 + l15;
            const float bs = bias[o];
            const unsigned int u0 = (unsigned int)f2h(acc[ot][0] + bs) |
                                    ((unsigned int)f2h(acc[ot][1] + bs) << 16);
            const unsigned int u1 = (unsigned int)f2h(acc[ot][2] + bs) |
                                    ((unsigned int)f2h(acc[ot][3] + bs) << 16);
            uint2 uv; uv.x = u0; uv.y = u1;
            *(uint2*)&Vt[o * 72 + wave * 16 + quad * 4] = uv;
        }
        __syncthreads();
        const int ch   = t & 7;
        const int orow = t >> 3;
#pragma unroll
        for (int pass = 0; pass < 8; pass++) {
            const int o = pass * 32 + orow;
            const short8 vv = *(const short8*)&Vt[o * 72 + ch * 8];
            *(short8*)&Vh[((size_t)b * C_DIM + o) * N_TOK + n0 + ch * 8] = vv;
        }
    }
}

// ---------------------------------------------------------------------------
// flash_kernel v10 (D'): synthesis of the validated pieces.
//  - r8 (v9b) proved: direct-global K/V frags = VMEM-latency-bound (260us,
//    MfmaUtil 16%) even at 2 waves/SIMD.  K/V must come from LDS.
//  - c-split (v9b-validated): oacc = 64 AGPR -> frees 64 regs vs v6.
//  - K/V staged via the v4/v6 2-barrier pipeline (validated): Ks 32KB full
//    K-tile + Vs 16KB c-HALF tile = 48KB -> 2 blocks/CU.
//  - Q register-resident (qf[16] = 64 VGPR), loaded ONCE per block from the
//    swizzled Qg blob (mapping validated in v9b).
//  Register budget: qf 64 + sv 32 + pf 16 + temps ~40 = ~150 arch + 64 AGPR
//  = ~215 <= 256 combined cap of (256,2) -> 2 waves/SIMD, no spill (v9b
//  demonstrated the cap-256 no-spill regime at demand ~190).
//  Per-wave-iter: 48 ds_read_b128 (vs v4's 64) feeding 48 MFMA at 2x
//  FLOP/read; LDS floor ~61us, MFMA floor (incl. 1.5x S-dup) ~43us.
// ---------------------------------------------------------------------------
template<int NS>
__global__ __launch_bounds__(256, 2) void flash_kernel(
    const unsigned short* __restrict__ Qg,   // swizzled [4][32][32][128][8]
    const unsigned short* __restrict__ Kg,   // fp16 [4][4096][256] (k+pos)
    const unsigned short* __restrict__ Vg,   // fp16 [4][256][4096]
    unsigned short* __restrict__ Op,         // fp16 [NS][4][256][4096]
    float* __restrict__ Lm)                  // [NS][4][4096] float2 (m,l)
{
    constexpr int NITER = N_TOK / (NS * 64);
    constexpr int SB    = (NS == 4) ? 2 : 1;

    __shared__ unsigned short Ks[64 * 256];   // 32KB K' tile [j][c]
    __shared__ unsigned short Vs[128 * 64];   // 16KB V c-half tile [cl][j]

    const int t    = threadIdx.x;
    const int wave = t >> 6;
    const int lane = t & 63;
    const int l31  = lane & 31;
    const int H    = lane >> 5;    // k-split half of 32x32x16 operands
    const int lk7  = lane & 7;     // LDS chunk-swizzle key (row&7)

    const int bid = blockIdx.x;
    const int b   = bid & 3;
    const int s   = (bid >> 2) & (NS - 1);
    const int r2  = bid >> (2 + SB);
    const int ch  = r2 & 1;          // c-half
    const int qt  = r2 >> 1;         // 0..31

    const size_t bbase = (size_t)b * N_TOK * C_DIM;
    const unsigned short* Kb = Kg + bbase;
    const unsigned short* Vb = Vg + bbase;

    // ---- Q fragments resident in registers (1 global read per block)
    half8 qf[16];
    {
        const unsigned short* Qw = Qg + bbase + (size_t)qt * 32768;
        const int qoff = (wave * 32 + l31) * 8;
#pragma unroll
        for (int ct = 0; ct < 16; ct++)
            qf[ct] = *(const half8*)&Qw[(ct * 2 + H) * 1024 + qoff];
    }

    floatx16 oacc[4];   // O^T[c = ch*128 + cb*32 + row(r,H)][q=l31]
#pragma unroll
    for (int cb = 0; cb < 4; cb++)
#pragma unroll
        for (int r = 0; r < 16; r++) oacc[cb][r] = 0.f;
    float m_i = -1e30f;
    float l_i = 0.f;

    const int jbase = s * (NITER * 64);

    // ---- preamble: stage K tile 0 (v6-validated pattern)
    {
        const int lr = lane >> 5, cp = lane & 31;
#pragma unroll
        for (int p = 0; p < 8; p++) {
            const int jl = wave * 16 + p * 2 + lr;
            g2l16(Kb + (size_t)(jbase + jl) * C_DIM + (cp ^ (jl & 7)) * 8,
                  &Ks[(wave * 16 + p * 2) * 256]);
        }
    }

    for (int ti = 0; ti < NITER; ti++) {
        const int j0 = jbase + ti * 64;

        __syncthreads();   // B1: K(ti) visible; PV(ti-1) V-reads done

        // ---- stage V c-half(ti) async (flies under S-MFMAs)
        {
            const int lr = lane >> 3, cp = lane & 7;
#pragma unroll
            for (int p = 0; p < 4; p++) {
                const int ob = (p * 4 + wave) * 8;      // local row 0..120
                const int o  = ch * 128 + ob + lr;      // global V row
                g2l16(Vb + (size_t)o * N_TOK + j0 + (cp ^ (o & 7)) * 8, &Vs[ob * 64]);
            }
        }

        // ---- S^T = K' Q^T (full c=256; A from Ks, B = qf regs)
        floatx16 sv0, sv1;
        {
            floatx16 a0, a1;
#pragma unroll
            for (int r = 0; r < 16; r++) { a0[r] = 0.f; a1[r] = 0.f; }
            __builtin_amdgcn_s_setprio(1);
#pragma unroll
            for (int ct = 0; ct < 16; ct++) {
                const int chx = ((ct * 2 + H) ^ lk7) * 8;
                const half8 k0 = *(const half8*)&Ks[l31 * 256 + chx];
                a0 = __builtin_amdgcn_mfma_f32_32x32x16_f16(k0, qf[ct], a0, 0, 0, 0);
                const half8 k1 = *(const half8*)&Ks[(32 + l31) * 256 + chx];
                a1 = __builtin_amdgcn_mfma_f32_32x32x16_f16(k1, qf[ct], a1, 0, 0, 0);
            }
            __builtin_amdgcn_s_setprio(0);
            sv0 = a0; sv1 = a1;
        }

        // ---- per-lane online softmax (32 j's/lane; partner lane^32)
        float mx = sv0[0];
#pragma unroll
        for (int r = 1; r < 16; r++) mx = fmaxf(mx, sv0[r]);
#pragma unroll
        for (int r = 0; r < 16; r++) mx = fmaxf(mx, sv1[r]);
        mx = fmaxf(mx, __shfl_xor(mx, 32));

        // T13 defer-max
        if (!__all(mx <= m_i + 8.f)) {
            const float mn    = fmaxf(m_i, mx);
            const float alpha = __expf(m_i - mn);
            m_i = mn;
            l_i *= alpha;
#pragma unroll
            for (int cb = 0; cb < 4; cb++)
#pragma unroll
                for (int r = 0; r < 16; r++) oacc[cb][r] *= alpha;
        }
        float ps = 0.f;
#pragma unroll
        for (int r = 0; r < 16; r++) {
            const float p = __expf(sv0[r] - m_i);
            sv0[r] = p; ps += p;
        }
#pragma unroll
        for (int r = 0; r < 16; r++) {
            const float p = __expf(sv1[r] - m_i);
            sv1[r] = p; ps += p;
        }
        l_i += ps;

        // ---- P^T -> PV B-frags (validated v6/v8/v9b butterfly)
        half8 pf0, pf1, pf2, pf3;
        {
            const unsigned int p0 = pack2h(sv0[0],  sv0[1]);
            const unsigned int p1 = pack2h(sv0[2],  sv0[3]);
            const unsigned int p2 = pack2h(sv0[4],  sv0[5]);
            const unsigned int p3 = pack2h(sv0[6],  sv0[7]);
            const unsigned int p4 = pack2h(sv0[8],  sv0[9]);
            const unsigned int p5 = pack2h(sv0[10], sv0[11]);
            const unsigned int p6 = pack2h(sv0[12], sv0[13]);
            const unsigned int p7 = pack2h(sv0[14], sv0[15]);
            const unsigned int s0 = __shfl_xor(p0, 32);
            const unsigned int s1 = __shfl_xor(p1, 32);
            const unsigned int s2 = __shfl_xor(p2, 32);
            const unsigned int s3 = __shfl_xor(p3, 32);
            const unsigned int s4 = __shfl_xor(p4, 32);
            const unsigned int s5 = __shfl_xor(p5, 32);
            const unsigned int s6 = __shfl_xor(p6, 32);
            const unsigned int s7 = __shfl_xor(p7, 32);
            union { unsigned int u[4]; half8 h; } a, c;
            a.u[0] = H ? s2 : p0;  a.u[1] = H ? s3 : p1;
            a.u[2] = H ? p2 : s0;  a.u[3] = H ? p3 : s1;
            c.u[0] = H ? s6 : p4;  c.u[1] = H ? s7 : p5;
            c.u[2] = H ? p6 : s4;  c.u[3] = H ? p7 : s5;
            pf0 = a.h; pf1 = c.h;
        }
        {
            const unsigned int p0 = pack2h(sv1[0],  sv1[1]);
            const unsigned int p1 = pack2h(sv1[2],  sv1[3]);
            const unsigned int p2 = pack2h(sv1[4],  sv1[5]);
            const unsigned int p3 = pack2h(sv1[6],  sv1[7]);
            const unsigned int p4 = pack2h(sv1[8],  sv1[9]);
            const unsigned int p5 = pack2h(sv1[10], sv1[11]);
            const unsigned int p6 = pack2h(sv1[12], sv1[13]);
            const unsigned int p7 = pack2h(sv1[14], sv1[15]);
            const unsigned int s0 = __shfl_xor(p0, 32);
            const unsigned int s1 = __shfl_xor(p1, 32);
            const unsigned int s2 = __shfl_xor(p2, 32);
            const unsigned int s3 = __shfl_xor(p3, 32);
            const unsigned int s4 = __shfl_xor(p4, 32);
            const unsigned int s5 = __shfl_xor(p5, 32);
            const unsigned int s6 = __shfl_xor(p6, 32);
            const unsigned int s7 = __shfl_xor(p7, 32);
            union { unsigned int u[4]; half8 h; } a, c;
            a.u[0] = H ? s2 : p0;  a.u[1] = H ? s3 : p1;
            a.u[2] = H ? p2 : s0;  a.u[3] = H ? p3 : s1;
            c.u[0] = H ? s6 : p4;  c.u[1] = H ? s7 : p5;
            c.u[2] = H ? p6 : s4;  c.u[3] = H ? p7 : s5;
            pf2 = a.h; pf3 = c.h;
        }

        __syncthreads();   // B2: V(ti) visible; all waves done reading K(ti)

        // ---- stage K(ti+1) async (flies under PV-MFMAs)
        if (ti < NITER - 1) {
            const int lr = lane >> 5, cp = lane & 31;
#pragma unroll
            for (int p = 0; p < 8; p++) {
                const int jl = wave * 16 + p * 2 + lr;
                g2l16(Kb + (size_t)(j0 + 64 + jl) * C_DIM + (cp ^ (jl & 7)) * 8,
                      &Ks[(wave * 16 + p * 2) * 256]);
            }
        }

        // ---- O^T += V P^T (A from Vs c-half, local rows)
        __builtin_amdgcn_s_setprio(1);
#pragma unroll
        for (int cb = 0; cb < 4; cb++) {
            const int vb = (cb * 32 + l31) * 64;
            const half8 av0 = *(const half8*)&Vs[vb + (((0 + H) ^ lk7) * 8)];
            oacc[cb] = __builtin_amdgcn_mfma_f32_32x32x16_f16(av0, pf0, oacc[cb], 0, 0, 0);
            const half8 av1 = *(const half8*)&Vs[vb + (((2 + H) ^ lk7) * 8)];
            oacc[cb] = __builtin_amdgcn_mfma_f32_32x32x16_f16(av1, pf1, oacc[cb], 0, 0, 0);
            const half8 av2 = *(const half8*)&Vs[vb + (((4 + H) ^ lk7) * 8)];
            oacc[cb] = __builtin_amdgcn_mfma_f32_32x32x16_f16(av2, pf2, oacc[cb], 0, 0, 0);
            const half8 av3 = *(const half8*)&Vs[vb + (((6 + H) ^ lk7) * 8)];
            oacc[cb] = __builtin_amdgcn_mfma_f32_32x32x16_f16(av3, pf3, oacc[cb], 0, 0, 0);
        }
        __builtin_amdgcn_s_setprio(0);
    }

    // ---- epilogue: unnormalized O^T fp16 + (m,l)
    unsigned short* Ob = Op + ((size_t)(s * 4 + b) * C_DIM) * N_TOK;
    const int n = qt * 128 + wave * 32 + l31;
#pragma unroll
    for (int cb = 0; cb < 4; cb++) {
#pragma unroll
        for (int r = 0; r < 16; r++) {
            const int c = ch * 128 + cb * 32 + (r & 3) + 8 * (r >> 2) + 4 * H;
            Ob[(size_t)c * N_TOK + n] = f2h(oacc[cb][r]);
        }
    }
    if (ch == 0) {
        float lt = l_i + __shfl_xor(l_i, 32);
        if (H == 0) {
            const size_t nb = (size_t)(s * 4 + b) * N_TOK + n;
            *(float2*)&Lm[nb * 2] = make_float2(m_i, lt);
        }
    }
}

// ---------------------------------------------------------------------------
// merge_kernel: out = gamma * (sum_s w_s O_s) / (sum_s w_s l_s) + x
// ---------------------------------------------------------------------------
template<int NS>
__global__ __launch_bounds__(256) void merge_kernel(
    const unsigned short* __restrict__ Op,
    const float* __restrict__ Lm,
    const float* __restrict__ x,
    const float* __restrict__ gamma,
    float* __restrict__ out)
{
    const int blk = blockIdx.x;          // 4096
    const int b   = blk >> 10;
    const int c   = (blk >> 2) & 255;
    const int nq  = blk & 3;
    const int n0  = nq * 1024 + threadIdx.x * 4;

    const size_t NEo = (size_t)4 * C_DIM * N_TOK;
    const size_t obase = ((size_t)b * C_DIM + c) * N_TOK + n0;

    float ms[NS][4], ls[NS][4], os[NS][4];
#pragma unroll
    for (int s = 0; s < NS; s++) {
        const uint2 u = *(const uint2*)&Op[s * NEo + obase];
        os[s][0] = h2f((unsigned short)(u.x & 0xffff));
        os[s][1] = h2f((unsigned short)(u.x >> 16));
        os[s][2] = h2f((unsigned short)(u.y & 0xffff));
        os[s][3] = h2f((unsigned short)(u.y >> 16));
        const float* Lms = Lm + (size_t)(s * 4 + b) * N_TOK * 2;
        const float4 A0 = *(const float4*)&Lms[n0 * 2];
        const float4 A1 = *(const float4*)&Lms[n0 * 2 + 4];
        ms[s][0] = A0.x; ls[s][0] = A0.y;
        ms[s][1] = A0.z; ls[s][1] = A0.w;
        ms[s][2] = A1.x; ls[s][2] = A1.y;
        ms[s][3] = A1.z; ls[s][3] = A1.w;
    }
    const float4 xv = *(const float4*)&x[obase];
    const float xin[4] = {xv.x, xv.y, xv.z, xv.w};
    const float g = gamma[0];

    float4 res;
    float* rp = (float*)&res;
#pragma unroll
    for (int i = 0; i < 4; i++) {
        float M = ms[0][i];
#pragma unroll
        for (int s = 1; s < NS; s++) M = fmaxf(M, ms[s][i]);
        float osum = 0.f, lsum = 0.f;
#pragma unroll
        for (int s = 0; s < NS; s++) {
            const float w = __expf(ms[s][i] - M);
            osum += w * os[s][i];
            lsum += w * ls[s][i];
        }
        rp[i] = g * osum / lsum + xin[i];
    }
    *(float4*)&out[obase] = res;
}

extern "C" void kernel_launch(void* const* d_in, const int* in_sizes, int n_in,
                              void* d_out, int out_size, void* d_ws, size_t ws_size,
                              hipStream_t stream) {
    const float* x     = (const float*)d_in[0];
    const float* Wq    = (const float*)d_in[1];
    const float* bq    = (const float*)d_in[2];
    const float* Wk    = (const float*)d_in[3];
    const float* bk    = (const float*)d_in[4];
    const float* Wv    = (const float*)d_in[5];
    const float* bv    = (const float*)d_in[6];
    const float* relh  = (const float*)d_in[7];
    const float* relw  = (const float*)d_in[8];
    const float* gamma = (const float*)d_in[9];
    float* out = (float*)d_out;

    const size_t NE = (size_t)4 * N_TOK * C_DIM;   // 4.19M elems

    // NS=4 needs: Op 4NE u16 + W 6*65536 u16 + QKV 3NE u16 + Lm 4*4*4096*2 f32
    const size_t need4 = ((size_t)7 * NE + 6 * 65536) * 2 + (size_t)4 * 4 * N_TOK * 2 * 4;
    const int NS = (ws_size >= need4) ? 4 : 2;

    // Region layout (Op overlays Xhi/Xlo: X dead before flash writes Op)
    unsigned short* Op  = (unsigned short*)d_ws;           // NS*NE u16
    unsigned short* Xhi = Op;                              // NE u16 (prep/proj only)
    unsigned short* Xlo = Op + NE;                         // NE u16
    unsigned short* Whi = Op + (size_t)NS * NE;            // 3*65536 u16
    unsigned short* Wlo = Whi + 3 * 65536;
    unsigned short* Qh  = Wlo + 3 * 65536;                 // NE u16 (fp16, swizzled)
    unsigned short* Kh  = Qh + NE;                         // NE u16 (fp16, [n][o])
    unsigned short* Vh  = Kh + NE;                         // NE u16 (fp16, [o][n])
    float* Lm = (float*)(Vh + NE);                         // NS*4*4096*2 floats

    hipLaunchKernelGGL(prep_kernel, dim3(1027), dim3(256), 0, stream,
                       x, Wq, Wk, Wv, Xhi, Xlo, Whi, Wlo);
    hipLaunchKernelGGL(proj_kernel, dim3(768), dim3(256), 0, stream,
                       Xhi, Xlo, Whi, Wlo, bq, bk, bv, relh, relw, Qh, Kh, Vh);
    if (NS == 4) {
        hipLaunchKernelGGL((flash_kernel<4>), dim3(1024), dim3(256), 0, stream,
                           Qh, Kh, Vh, Op, Lm);
        hipLaunchKernelGGL((merge_kernel<4>), dim3(4096), dim3(256), 0, stream,
                           Op, Lm, x, gamma, out);
    } else {
        hipLaunchKernelGGL((flash_kernel<2>), dim3(512), dim3(256), 0, stream,
                           Qh, Kh, Vh, Op, Lm);
        hipLaunchKernelGGL((merge_kernel<2>), dim3(4096), dim3(256), 0, stream,
                           Op, Lm, x, gamma, out);
    }
}

// Round 10
// 290.073 us; speedup vs baseline: 1.3703x; 1.3326x over previous
//
#include <hip/hip_runtime.h>
#include <stdint.h>

#define N_TOK 4096
#define C_DIM 256

typedef __attribute__((ext_vector_type(8))) short short8;
typedef __attribute__((ext_vector_type(8))) _Float16 half8;
typedef __attribute__((ext_vector_type(4))) float floatx4;
typedef __attribute__((ext_vector_type(16))) float floatx16;
typedef __attribute__((ext_vector_type(4))) unsigned short ushort4v;

__device__ __forceinline__ unsigned short bf16_rne(float f) {
    union { float f; unsigned int u; } v; v.f = f;
    unsigned int u = v.u;
    unsigned int rounded = u + 0x7FFFu + ((u >> 16) & 1u);
    return (unsigned short)(rounded >> 16);
}
__device__ __forceinline__ float bf16_to_f(unsigned short h) {
    union { unsigned int u; float f; } v; v.u = ((unsigned int)h) << 16;
    return v.f;
}
__device__ __forceinline__ void split_bf16(float f, unsigned short& h, unsigned short& l) {
    h = bf16_rne(f);
    l = bf16_rne(f - bf16_to_f(h));
}
__device__ __forceinline__ unsigned short f2h(float f) {
    union { _Float16 h; unsigned short u; } v; v.h = (_Float16)f; return v.u;
}
__device__ __forceinline__ float h2f(unsigned short u) {
    union { unsigned short u; _Float16 h; } v; v.u = u; return (float)v.h;
}
// pack two floats -> half2 (RNE)
__device__ __forceinline__ unsigned int pack2h(float a, float b) {
    union { _Float16 h[2]; unsigned int u; } v;
    v.h[0] = (_Float16)a; v.h[1] = (_Float16)b;
    return v.u;
}
// async global->LDS 16B/lane; LDS dest = wave-uniform base + lane*16
__device__ __forceinline__ void g2l16(const void* g, void* l) {
    __builtin_amdgcn_global_load_lds(
        (const __attribute__((address_space(1))) void*)g,
        (__attribute__((address_space(3))) void*)l, 16, 0, 0);
}

// ---------------------------------------------------------------------------
// prep_kernel: one-time split/transpose (bf16 hi/lo pairs for fp32-accurate
// projection GEMM).  (unchanged)
// ---------------------------------------------------------------------------
__global__ __launch_bounds__(256) void prep_kernel(
    const float* __restrict__ x,
    const float* __restrict__ Wq, const float* __restrict__ Wk, const float* __restrict__ Wv,
    unsigned short* __restrict__ Xhi, unsigned short* __restrict__ Xlo,
    unsigned short* __restrict__ Whi, unsigned short* __restrict__ Wlo)
{
    const int t = threadIdx.x;
    if (blockIdx.x >= 1024) {
        const int pj = blockIdx.x - 1024;
        const float* W = (pj == 0) ? Wq : (pj == 1) ? Wk : Wv;
        unsigned short* dh = Whi + pj * 65536;
        unsigned short* dl = Wlo + pj * 65536;
        for (int it = 0; it < 64; it++) {
            const int idx = it * 1024 + t * 4;
            const float4 w = *(const float4*)&W[idx];
            unsigned short h0, l0, h1, l1, h2, l2, h3, l3;
            split_bf16(w.x, h0, l0); split_bf16(w.y, h1, l1);
            split_bf16(w.z, h2, l2); split_bf16(w.w, h3, l3);
            ushort4v vh; vh[0] = h0; vh[1] = h1; vh[2] = h2; vh[3] = h3;
            ushort4v vl; vl[0] = l0; vl[1] = l1; vl[2] = l2; vl[3] = l3;
            *(ushort4v*)&dh[idx] = vh;
            *(ushort4v*)&dl[idx] = vl;
        }
        return;
    }
    __shared__ float Xs[64 * 65];   // pitch 65: conflict-free transpose
    const int b  = blockIdx.x >> 8;
    const int ct = (blockIdx.x >> 6) & 3;
    const int nt = blockIdx.x & 63;
    const int c0 = ct * 64, n0 = nt * 64;
    {
        const int nch = t & 15, cr = t >> 4;
#pragma unroll
        for (int pass = 0; pass < 4; pass++) {
            const int c = pass * 16 + cr;
            const float4 v = *(const float4*)&x[((size_t)(b * C_DIM + c0 + c)) * N_TOK + n0 + nch * 4];
            float* row = &Xs[c * 65 + nch * 4];
            row[0] = v.x; row[1] = v.y; row[2] = v.z; row[3] = v.w;
        }
    }
    __syncthreads();
    {
        const int n = t >> 2, cc = t & 3;
        short8 vh0, vl0, vh1, vl1;
#pragma unroll
        for (int i = 0; i < 8; i++) {
            unsigned short h, l;
            split_bf16(Xs[(cc * 16 + i) * 65 + n], h, l);
            vh0[i] = (short)h; vl0[i] = (short)l;
        }
#pragma unroll
        for (int i = 0; i < 8; i++) {
            unsigned short h, l;
            split_bf16(Xs[(cc * 16 + 8 + i) * 65 + n], h, l);
            vh1[i] = (short)h; vl1[i] = (short)l;
        }
        const size_t off = ((size_t)b * N_TOK + n0 + n) * C_DIM + c0 + cc * 16;
        *(short8*)&Xhi[off] = vh0; *(short8*)&Xhi[off + 8] = vh1;
        *(short8*)&Xlo[off] = vl0; *(short8*)&Xlo[off + 8] = vl1;
    }
}

// ---------------------------------------------------------------------------
// proj_kernel: Out[n,o] = sum_c x[n,c]*W[o,c] + bias (+pos for K').
// Q swizzled: Qh[b][qt=n>>7][phase=o>>3][q=n&127][i=o&7]
// K row-major [n][o] (k+pos), V [o][n]  (round-2 layouts for LDS staging)
// ---------------------------------------------------------------------------
__global__ __launch_bounds__(256) void proj_kernel(
    const unsigned short* __restrict__ Xhi, const unsigned short* __restrict__ Xlo,
    const unsigned short* __restrict__ Whi, const unsigned short* __restrict__ Wlo,
    const float* __restrict__ bq, const float* __restrict__ bk, const float* __restrict__ bv,
    const float* __restrict__ relh, const float* __restrict__ relw,
    unsigned short* __restrict__ Qh,
    unsigned short* __restrict__ Kh,
    unsigned short* __restrict__ Vh)
{
    __shared__ unsigned short SM[20480];   // 40KB carve
    unsigned short* Ah = SM;               // [64][32]
    unsigned short* Al = SM + 2048;
    unsigned short* Bh = SM + 4096;        // [256][32]
    unsigned short* Bl = SM + 12288;

    const int t    = threadIdx.x;
    const int wave = t >> 6;
    const int lane = t & 63;
    const int l15  = lane & 15;
    const int quad = lane >> 4;

    const int bp   = blockIdx.x >> 6;
    const int proj = bp % 3;
    const int b    = bp / 3;
    const int n0   = (blockIdx.x & 63) * 64;

    const unsigned short* Xh = Xhi + ((size_t)b * N_TOK + n0) * C_DIM;
    const unsigned short* Xl = Xlo + ((size_t)b * N_TOK + n0) * C_DIM;
    const unsigned short* Wh = Whi + proj * 65536;
    const unsigned short* Wl = Wlo + proj * 65536;
    const float* bias = (proj == 0) ? bq : (proj == 1) ? bk : bv;
    const bool needlo = (proj < 2);

    floatx4 acc[16];
#pragma unroll
    for (int i = 0; i < 16; i++) acc[i] = (floatx4){0.f, 0.f, 0.f, 0.f};

    for (int c0 = 0; c0 < 256; c0 += 32) {
        {
            const int lr = lane >> 2, cp = lane & 3;
            const int key = (lr ^ (lr >> 2)) & 3;
            const int r = wave * 16 + lr;
            g2l16(Xh + (size_t)r * C_DIM + c0 + (cp ^ key) * 8, &Ah[wave * 512]);
            if (needlo) g2l16(Xl + (size_t)r * C_DIM + c0 + (cp ^ key) * 8, &Al[wave * 512]);
#pragma unroll
            for (int p = 0; p < 4; p++) {
                const int rb = (p * 4 + wave) * 16;
                const int rr = rb + lr;
                g2l16(Wh + (size_t)rr * 256 + c0 + (cp ^ key) * 8, &Bh[rb * 32]);
                if (needlo) g2l16(Wl + (size_t)rr * 256 + c0 + (cp ^ key) * 8, &Bl[rb * 32]);
            }
        }
        __syncthreads();

        const int akey = (l15 ^ (l15 >> 2)) & 3;
        const int arow = (wave * 16 + l15) * 32 + ((quad ^ akey) * 8);
        const short8 a_h = *(const short8*)&Ah[arow];
        short8 a_l;
        if (needlo) a_l = *(const short8*)&Al[arow];
#pragma unroll
        for (int ot = 0; ot < 16; ot++) {
            const int brow = (ot * 16 + l15) * 32 + ((quad ^ akey) * 8);
            const short8 b_h = *(const short8*)&Bh[brow];
            acc[ot] = __builtin_amdgcn_mfma_f32_16x16x32_bf16(a_h, b_h, acc[ot], 0, 0, 0);
            if (needlo) {
                const short8 b_l = *(const short8*)&Bl[brow];
                acc[ot] = __builtin_amdgcn_mfma_f32_16x16x32_bf16(a_l, b_h, acc[ot], 0, 0, 0);
                acc[ot] = __builtin_amdgcn_mfma_f32_16x16x32_bf16(a_h, b_l, acc[ot], 0, 0, 0);
            }
        }
        __syncthreads();
    }

    // ---- epilogue (all fp16 outputs) ----
    const int h0 = n0 >> 6;   // pos[c][n] = relh[c][n>>6] + relw[c][n&63]
    if (proj == 0) {
        // swizzled Q: [qt][phase=o>>3][q128][i=o&7]
        unsigned short* Og = Qh + (size_t)b * N_TOK * C_DIM;
#pragma unroll
        for (int ot = 0; ot < 16; ot++) {
            const int o = ot * 16 + l15;
            const float bs = bias[o];
            const int phase = o >> 3;
            const int ii    = o & 7;
#pragma unroll
            for (int r = 0; r < 4; r++) {
                const int n  = n0 + wave * 16 + quad * 4 + r;
                const int qt = n >> 7, q128 = n & 127;
                Og[(size_t)qt * 32768 + phase * 1024 + q128 * 8 + ii] = f2h(acc[ot][r] + bs);
            }
        }
    } else if (proj == 1) {
        // K' row-major [n][o]
        unsigned short* Og = Kh + ((size_t)b * N_TOK + n0) * C_DIM;
#pragma unroll
        for (int ot = 0; ot < 16; ot++) {
            const int o = ot * 16 + l15;
            const float bs = bias[o];
            const float ph = relh[o * 64 + h0];
#pragma unroll
            for (int r = 0; r < 4; r++) {
                const int nl = wave * 16 + quad * 4 + r;
                Og[(size_t)nl * C_DIM + o] = f2h(acc[ot][r] + bs + ph + relw[o * 64 + nl]);
            }
        }
    } else {
        // V [o][n] via LDS transpose
        unsigned short* Vt = SM;
#pragma unroll
        for (int ot = 0; ot < 16; ot++) {
            const int o = ot * 16 + l15;
            const float bs = bias[o];
            const unsigned int u0 = (unsigned int)f2h(acc[ot][0] + bs) |
                                    ((unsigned int)f2h(acc[ot][1] + bs) << 16);
            const unsigned int u1 = (unsigned int)f2h(acc[ot][2] + bs) |
                                    ((unsigned int)f2h(acc[ot][3] + bs) << 16);
            uint2 uv; uv.x = u0; uv.y = u1;
            *(uint2*)&Vt[o * 72 + wave * 16 + quad * 4] = uv;
        }
        __syncthreads();
        const int ch   = t & 7;
        const int orow = t >> 3;
#pragma unroll
        for (int pass = 0; pass < 8; pass++) {
            const int o = pass * 32 + orow;
            const short8 vv = *(const short8*)&Vt[o * 72 + ch * 8];
            *(short8*)&Vh[((size_t)b * C_DIM + o) * N_TOK + n0 + ch * 8] = vv;
        }
    }
}

// ---------------------------------------------------------------------------
// flash_kernel v11: v10 (round-9, numerically validated) with the arch-VGPR
// budget actually met.
// r9 diagnosis: (256,2) => unified cap 256; compiler split 128 arch + 128
// AGPR (64 oacc + 64 spill slots), arch demand ~190 (qf[16]=64 the biggest
// consumer) => ~240MB scratch traffic, 233us.
// Fix: qf 64 -> 32 regs.  Q fragments are RELOADED each iteration in two
// batches of 8 from the L2-resident swizzled Q blob (64KB/block, hot).
// The 2-pass loop is NOT unrolled => the 8-reg batch array is reused
// (inner loop fully unrolled: no runtime-indexed registers).  Extra cost:
// 16 global b128/iter/lane ~ 1GB L2 reads ~ 30us of L2 BW, overlapped with
// the LDS/MFMA pipes (~200cy latency hides under 16 MFMAs ~ 512cy/batch).
// Arch demand now ~sv32 + qh32 + pf16 + temps ~ 120-135 <= 128 (+64 AGPR
// spill-slot cushion).  K/V LDS staging, butterfly, PV, epilogue unchanged.
// ---------------------------------------------------------------------------
template<int NS>
__global__ __launch_bounds__(256, 2) void flash_kernel(
    const unsigned short* __restrict__ Qg,   // swizzled [4][32][32][128][8]
    const unsigned short* __restrict__ Kg,   // fp16 [4][4096][256] (k+pos)
    const unsigned short* __restrict__ Vg,   // fp16 [4][256][4096]
    unsigned short* __restrict__ Op,         // fp16 [NS][4][256][4096]
    float* __restrict__ Lm)                  // [NS][4][4096] float2 (m,l)
{
    constexpr int NITER = N_TOK / (NS * 64);
    constexpr int SB    = (NS == 4) ? 2 : 1;

    __shared__ unsigned short Ks[64 * 256];   // 32KB K' tile [j][c]
    __shared__ unsigned short Vs[128 * 64];   // 16KB V c-half tile [cl][j]

    const int t    = threadIdx.x;
    const int wave = t >> 6;
    const int lane = t & 63;
    const int l31  = lane & 31;
    const int H    = lane >> 5;    // k-split half of 32x32x16 operands
    const int lk7  = lane & 7;     // LDS chunk-swizzle key (row&7)

    const int bid = blockIdx.x;
    const int b   = bid & 3;
    const int s   = (bid >> 2) & (NS - 1);
    const int r2  = bid >> (2 + SB);
    const int ch  = r2 & 1;          // c-half
    const int qt  = r2 >> 1;         // 0..31

    const size_t bbase = (size_t)b * N_TOK * C_DIM;
    const unsigned short* Kb = Kg + bbase;
    const unsigned short* Vb = Vg + bbase;
    const unsigned short* Qw = Qg + bbase + (size_t)qt * 32768;
    const int qoff = (wave * 32 + l31) * 8;

    floatx16 oacc[4];   // O^T[c = ch*128 + cb*32 + row(r,H)][q=l31]
#pragma unroll
    for (int cb = 0; cb < 4; cb++)
#pragma unroll
        for (int r = 0; r < 16; r++) oacc[cb][r] = 0.f;
    float m_i = -1e30f;
    float l_i = 0.f;

    const int jbase = s * (NITER * 64);

    // ---- preamble: stage K tile 0
    {
        const int lr = lane >> 5, cp = lane & 31;
#pragma unroll
        for (int p = 0; p < 8; p++) {
            const int jl = wave * 16 + p * 2 + lr;
            g2l16(Kb + (size_t)(jbase + jl) * C_DIM + (cp ^ (jl & 7)) * 8,
                  &Ks[(wave * 16 + p * 2) * 256]);
        }
    }

    for (int ti = 0; ti < NITER; ti++) {
        const int j0 = jbase + ti * 64;

        __syncthreads();   // B1: K(ti) visible; PV(ti-1) V-reads done

        // ---- stage V c-half(ti) async (flies under S-MFMAs)
        {
            const int lr = lane >> 3, cp = lane & 7;
#pragma unroll
            for (int p = 0; p < 4; p++) {
                const int ob = (p * 4 + wave) * 8;      // local row 0..120
                const int o  = ch * 128 + ob + lr;      // global V row
                g2l16(Vb + (size_t)o * N_TOK + j0 + (cp ^ (o & 7)) * 8, &Vs[ob * 64]);
            }
        }

        // ---- S^T = K' Q^T in TWO c-halves; Q frags reloaded from L2 each
        // half (batch of 8 regs, loop NOT unrolled -> register reuse)
        floatx16 sv0, sv1;
        {
            floatx16 a0, a1;
#pragma unroll
            for (int r = 0; r < 16; r++) { a0[r] = 0.f; a1[r] = 0.f; }
#pragma unroll 1
            for (int hf = 0; hf < 2; hf++) {
                half8 qh[8];
#pragma unroll
                for (int c2 = 0; c2 < 8; c2++)
                    qh[c2] = *(const half8*)&Qw[((hf * 8 + c2) * 2 + H) * 1024 + qoff];
                __builtin_amdgcn_s_setprio(1);
#pragma unroll
                for (int c2 = 0; c2 < 8; c2++) {
                    const int ct  = hf * 8 + c2;
                    const int chx = ((ct * 2 + H) ^ lk7) * 8;
                    const half8 k0 = *(const half8*)&Ks[l31 * 256 + chx];
                    a0 = __builtin_amdgcn_mfma_f32_32x32x16_f16(k0, qh[c2], a0, 0, 0, 0);
                    const half8 k1 = *(const half8*)&Ks[(32 + l31) * 256 + chx];
                    a1 = __builtin_amdgcn_mfma_f32_32x32x16_f16(k1, qh[c2], a1, 0, 0, 0);
                }
                __builtin_amdgcn_s_setprio(0);
            }
            sv0 = a0; sv1 = a1;
        }

        // ---- per-lane online softmax (32 j's/lane; partner lane^32)
        float mx = sv0[0];
#pragma unroll
        for (int r = 1; r < 16; r++) mx = fmaxf(mx, sv0[r]);
#pragma unroll
        for (int r = 0; r < 16; r++) mx = fmaxf(mx, sv1[r]);
        mx = fmaxf(mx, __shfl_xor(mx, 32));

        // T13 defer-max
        if (!__all(mx <= m_i + 8.f)) {
            const float mn    = fmaxf(m_i, mx);
            const float alpha = __expf(m_i - mn);
            m_i = mn;
            l_i *= alpha;
#pragma unroll
            for (int cb = 0; cb < 4; cb++)
#pragma unroll
                for (int r = 0; r < 16; r++) oacc[cb][r] *= alpha;
        }
        float ps = 0.f;
#pragma unroll
        for (int r = 0; r < 16; r++) {
            const float p = __expf(sv0[r] - m_i);
            sv0[r] = p; ps += p;
        }
#pragma unroll
        for (int r = 0; r < 16; r++) {
            const float p = __expf(sv1[r] - m_i);
            sv1[r] = p; ps += p;
        }
        l_i += ps;

        // ---- P^T -> PV B-frags (validated v6/v8/v9b butterfly)
        half8 pf0, pf1, pf2, pf3;
        {
            const unsigned int p0 = pack2h(sv0[0],  sv0[1]);
            const unsigned int p1 = pack2h(sv0[2],  sv0[3]);
            const unsigned int p2 = pack2h(sv0[4],  sv0[5]);
            const unsigned int p3 = pack2h(sv0[6],  sv0[7]);
            const unsigned int p4 = pack2h(sv0[8],  sv0[9]);
            const unsigned int p5 = pack2h(sv0[10], sv0[11]);
            const unsigned int p6 = pack2h(sv0[12], sv0[13]);
            const unsigned int p7 = pack2h(sv0[14], sv0[15]);
            const unsigned int s0 = __shfl_xor(p0, 32);
            const unsigned int s1 = __shfl_xor(p1, 32);
            const unsigned int s2 = __shfl_xor(p2, 32);
            const unsigned int s3 = __shfl_xor(p3, 32);
            const unsigned int s4 = __shfl_xor(p4, 32);
            const unsigned int s5 = __shfl_xor(p5, 32);
            const unsigned int s6 = __shfl_xor(p6, 32);
            const unsigned int s7 = __shfl_xor(p7, 32);
            union { unsigned int u[4]; half8 h; } a, c;
            a.u[0] = H ? s2 : p0;  a.u[1] = H ? s3 : p1;
            a.u[2] = H ? p2 : s0;  a.u[3] = H ? p3 : s1;
            c.u[0] = H ? s6 : p4;  c.u[1] = H ? s7 : p5;
            c.u[2] = H ? p6 : s4;  c.u[3] = H ? p7 : s5;
            pf0 = a.h; pf1 = c.h;
        }
        {
            const unsigned int p0 = pack2h(sv1[0],  sv1[1]);
            const unsigned int p1 = pack2h(sv1[2],  sv1[3]);
            const unsigned int p2 = pack2h(sv1[4],  sv1[5]);
            const unsigned int p3 = pack2h(sv1[6],  sv1[7]);
            const unsigned int p4 = pack2h(sv1[8],  sv1[9]);
            const unsigned int p5 = pack2h(sv1[10], sv1[11]);
            const unsigned int p6 = pack2h(sv1[12], sv1[13]);
            const unsigned int p7 = pack2h(sv1[14], sv1[15]);
            const unsigned int s0 = __shfl_xor(p0, 32);
            const unsigned int s1 = __shfl_xor(p1, 32);
            const unsigned int s2 = __shfl_xor(p2, 32);
            const unsigned int s3 = __shfl_xor(p3, 32);
            const unsigned int s4 = __shfl_xor(p4, 32);
            const unsigned int s5 = __shfl_xor(p5, 32);
            const unsigned int s6 = __shfl_xor(p6, 32);
            const unsigned int s7 = __shfl_xor(p7, 32);
            union { unsigned int u[4]; half8 h; } a, c;
            a.u[0] = H ? s2 : p0;  a.u[1] = H ? s3 : p1;
            a.u[2] = H ? p2 : s0;  a.u[3] = H ? p3 : s1;
            c.u[0] = H ? s6 : p4;  c.u[1] = H ? s7 : p5;
            c.u[2] = H ? p6 : s4;  c.u[3] = H ? p7 : s5;
            pf2 = a.h; pf3 = c.h;
        }

        __syncthreads();   // B2: V(ti) visible; all waves done reading K(ti)

        // ---- stage K(ti+1) async (flies under PV-MFMAs)
        if (ti < NITER - 1) {
            const int lr = lane >> 5, cp = lane & 31;
#pragma unroll
            for (int p = 0; p < 8; p++) {
                const int jl = wave * 16 + p * 2 + lr;
                g2l16(Kb + (size_t)(j0 + 64 + jl) * C_DIM + (cp ^ (jl & 7)) * 8,
                      &Ks[(wave * 16 + p * 2) * 256]);
            }
        }

        // ---- O^T += V P^T (A from Vs c-half, local rows)
        __builtin_amdgcn_s_setprio(1);
#pragma unroll
        for (int cb = 0; cb < 4; cb++) {
            const int vb = (cb * 32 + l31) * 64;
            const half8 av0 = *(const half8*)&Vs[vb + (((0 + H) ^ lk7) * 8)];
            oacc[cb] = __builtin_amdgcn_mfma_f32_32x32x16_f16(av0, pf0, oacc[cb], 0, 0, 0);
            const half8 av1 = *(const half8*)&Vs[vb + (((2 + H) ^ lk7) * 8)];
            oacc[cb] = __builtin_amdgcn_mfma_f32_32x32x16_f16(av1, pf1, oacc[cb], 0, 0, 0);
            const half8 av2 = *(const half8*)&Vs[vb + (((4 + H) ^ lk7) * 8)];
            oacc[cb] = __builtin_amdgcn_mfma_f32_32x32x16_f16(av2, pf2, oacc[cb], 0, 0, 0);
            const half8 av3 = *(const half8*)&Vs[vb + (((6 + H) ^ lk7) * 8)];
            oacc[cb] = __builtin_amdgcn_mfma_f32_32x32x16_f16(av3, pf3, oacc[cb], 0, 0, 0);
        }
        __builtin_amdgcn_s_setprio(0);
    }

    // ---- epilogue: unnormalized O^T fp16 + (m,l)
    unsigned short* Ob = Op + ((size_t)(s * 4 + b) * C_DIM) * N_TOK;
    const int n = qt * 128 + wave * 32 + l31;
#pragma unroll
    for (int cb = 0; cb < 4; cb++) {
#pragma unroll
        for (int r = 0; r < 16; r++) {
            const int c = ch * 128 + cb * 32 + (r & 3) + 8 * (r >> 2) + 4 * H;
            Ob[(size_t)c * N_TOK + n] = f2h(oacc[cb][r]);
        }
    }
    if (ch == 0) {
        float lt = l_i + __shfl_xor(l_i, 32);
        if (H == 0) {
            const size_t nb = (size_t)(s * 4 + b) * N_TOK + n;
            *(float2*)&Lm[nb * 2] = make_float2(m_i, lt);
        }
    }
}

// ---------------------------------------------------------------------------
// merge_kernel: out = gamma * (sum_s w_s O_s) / (sum_s w_s l_s) + x
// ---------------------------------------------------------------------------
template<int NS>
__global__ __launch_bounds__(256) void merge_kernel(
    const unsigned short* __restrict__ Op,
    const float* __restrict__ Lm,
    const float* __restrict__ x,
    const float* __restrict__ gamma,
    float* __restrict__ out)
{
    const int blk = blockIdx.x;          // 4096
    const int b   = blk >> 10;
    const int c   = (blk >> 2) & 255;
    const int nq  = blk & 3;
    const int n0  = nq * 1024 + threadIdx.x * 4;

    const size_t NEo = (size_t)4 * C_DIM * N_TOK;
    const size_t obase = ((size_t)b * C_DIM + c) * N_TOK + n0;

    float ms[NS][4], ls[NS][4], os[NS][4];
#pragma unroll
    for (int s = 0; s < NS; s++) {
        const uint2 u = *(const uint2*)&Op[s * NEo + obase];
        os[s][0] = h2f((unsigned short)(u.x & 0xffff));
        os[s][1] = h2f((unsigned short)(u.x >> 16));
        os[s][2] = h2f((unsigned short)(u.y & 0xffff));
        os[s][3] = h2f((unsigned short)(u.y >> 16));
        const float* Lms = Lm + (size_t)(s * 4 + b) * N_TOK * 2;
        const float4 A0 = *(const float4*)&Lms[n0 * 2];
        const float4 A1 = *(const float4*)&Lms[n0 * 2 + 4];
        ms[s][0] = A0.x; ls[s][0] = A0.y;
        ms[s][1] = A0.z; ls[s][1] = A0.w;
        ms[s][2] = A1.x; ls[s][2] = A1.y;
        ms[s][3] = A1.z; ls[s][3] = A1.w;
    }
    const float4 xv = *(const float4*)&x[obase];
    const float xin[4] = {xv.x, xv.y, xv.z, xv.w};
    const float g = gamma[0];

    float4 res;
    float* rp = (float*)&res;
#pragma unroll
    for (int i = 0; i < 4; i++) {
        float M = ms[0][i];
#pragma unroll
        for (int s = 1; s < NS; s++) M = fmaxf(M, ms[s][i]);
        float osum = 0.f, lsum = 0.f;
#pragma unroll
        for (int s = 0; s < NS; s++) {
            const float w = __expf(ms[s][i] - M);
            osum += w * os[s][i];
            lsum += w * ls[s][i];
        }
        rp[i] = g * osum / lsum + xin[i];
    }
    *(float4*)&out[obase] = res;
}

extern "C" void kernel_launch(void* const* d_in, const int* in_sizes, int n_in,
                              void* d_out, int out_size, void* d_ws, size_t ws_size,
                              hipStream_t stream) {
    const float* x     = (const float*)d_in[0];
    const float* Wq    = (const float*)d_in[1];
    const float* bq    = (const float*)d_in[2];
    const float* Wk    = (const float*)d_in[3];
    const float* bk    = (const float*)d_in[4];
    const float* Wv    = (const float*)d_in[5];
    const float* bv    = (const float*)d_in[6];
    const float* relh  = (const float*)d_in[7];
    const float* relw  = (const float*)d_in[8];
    const float* gamma = (const float*)d_in[9];
    float* out = (float*)d_out;

    const size_t NE = (size_t)4 * N_TOK * C_DIM;   // 4.19M elems

    // NS=4 needs: Op 4NE u16 + W 6*65536 u16 + QKV 3NE u16 + Lm 4*4*4096*2 f32
    const size_t need4 = ((size_t)7 * NE + 6 * 65536) * 2 + (size_t)4 * 4 * N_TOK * 2 * 4;
    const int NS = (ws_size >= need4) ? 4 : 2;

    // Region layout (Op overlays Xhi/Xlo: X dead before flash writes Op)
    unsigned short* Op  = (unsigned short*)d_ws;           // NS*NE u16
    unsigned short* Xhi = Op;                              // NE u16 (prep/proj only)
    unsigned short* Xlo = Op + NE;                         // NE u16
    unsigned short* Whi = Op + (size_t)NS * NE;            // 3*65536 u16
    unsigned short* Wlo = Whi + 3 * 65536;
    unsigned short* Qh  = Wlo + 3 * 65536;                 // NE u16 (fp16, swizzled)
    unsigned short* Kh  = Qh + NE;                         // NE u16 (fp16, [n][o])
    unsigned short* Vh  = Kh + NE;                         // NE u16 (fp16, [o][n])
    float* Lm = (float*)(Vh + NE);                         // NS*4*4096*2 floats

    hipLaunchKernelGGL(prep_kernel, dim3(1027), dim3(256), 0, stream,
                       x, Wq, Wk, Wv, Xhi, Xlo, Whi, Wlo);
    hipLaunchKernelGGL(proj_kernel, dim3(768), dim3(256), 0, stream,
                       Xhi, Xlo, Whi, Wlo, bq, bk, bv, relh, relw, Qh, Kh, Vh);
    if (NS == 4) {
        hipLaunchKernelGGL((flash_kernel<4>), dim3(1024), dim3(256), 0, stream,
                           Qh, Kh, Vh, Op, Lm);
        hipLaunchKernelGGL((merge_kernel<4>), dim3(4096), dim3(256), 0, stream,
                           Op, Lm, x, gamma, out);
    } else {
        hipLaunchKernelGGL((flash_kernel<2>), dim3(512), dim3(256), 0, stream,
                           Qh, Kh, Vh, Op, Lm);
        hipLaunchKernelGGL((merge_kernel<2>), dim3(4096), dim3(256), 0, stream,
                           Op, Lm, x, gamma, out);
    }
}